// Round 3
// baseline (459.026 us; speedup 1.0000x reference)
//
#include <hip/hip_runtime.h>
#include <math.h>

#define BATCH 32768
#define SEQLEN 200
#define PSTEPS 50
#define HID 32
#define LDS_PAD 36   // float row stride 36 -> mild bank aliasing only (m136)

typedef __attribute__((ext_vector_type(2))) _Float16 half2v;
typedef __attribute__((ext_vector_type(8))) _Float16 half8v;
typedef __attribute__((ext_vector_type(2))) __fp16   fp16x2;   // cvt_pkrtz return type
typedef __attribute__((ext_vector_type(4))) float floatx4;

#define EXP2 __builtin_amdgcn_exp2f      // v_exp_f32: 2^x
#define RCPF __builtin_amdgcn_rcpf       // v_rcp_f32
#define PKRTZ __builtin_amdgcn_cvt_pkrtz // v_cvt_pkrtz_f16_f32
#define MED3 __builtin_amdgcn_fmed3f     // v_med3_f32

#define L1C 1.4426950408889634f          // log2(e)
#define L2C 2.8853900817779268f          // 2*log2(e)

union H8 { unsigned int u[4]; half8v h; half2v h2[4]; };
union HU { fp16x2 h; unsigned int u; };

__device__ __forceinline__ unsigned int pk(float a, float b) {
    HU t; t.h = PKRTZ(a, b); return t.u;
}

// R13: two-failed-rounds post-mortem says the cross-wave cell-split is
// cursed (R11 asm-barrier 0.68, R12 __syncthreads 0.94 — different wrong
// answers from identical dataflow => exchange delivers garbage). Revert to
// the EXACT hardware-verified R10 closed loop (one wave = private 16-batch
// group, private LDS h-region, NO barriers), and instead raise per-SIMD ILP:
// each wave owns TWO independent batch-groups A,B, textually duplicated and
// program-order interleaved (MFMA-A, MFMA-B, gates-A, gates-B). Group B's
// instructions fill group A's MFMA/LDS/trans latency windows. Weights are
// shared between the groups (64 VGPRs amortized). 1024 waves = 1/SIMD;
// a single wave saturates the VALU pipe given this ILP (wave64 VALU op = 2
// cycles occupancy, 1/cycle issue).
// Per-group math is token-for-token R10: exp-domain scales folded into
// weights, paired rcp, med3 tanh clamp (EXACT: tanh(12)==1.0f in fp32),
// state c unclamped, bias hi/lo split, decode f-gate skipped.
// C layout: row(batch)=quad*4+reg, col(gate)=lane&15; A: m=lane&15, k=quad*8+j.
__global__ __launch_bounds__(256, 1)
void lstm_mfma_kernel(const float* __restrict__ hist, const float* __restrict__ W_ih,
                      const float* __restrict__ W_hh, const float* __restrict__ b_ih,
                      const float* __restrict__ b_hh, const float* __restrict__ W_pred,
                      const float* __restrict__ b_pred, float* __restrict__ out)
{
    const int lane = threadIdx.x & 63;
    const int wv   = threadIdx.x >> 6;
    const int m    = lane & 15;
    const int quad = lane >> 4;
    const int gidx  = blockIdx.x * 4 + wv;   // 0..1023
    const int elemA = gidx * 32;
    const int elemB = elemA + 16;

    __shared__ __align__(16) float h_lds_all[4][2][16][LDS_PAD];
    float (*hlA)[LDS_PAD] = h_lds_all[wv][0];   // per-wave private: no barriers ever
    float (*hlB)[LDS_PAD] = h_lds_all[wv][1];

    // ---- resident weight fragments (f16, exp-scale folded; tiles 0,1=i 2,3=f 4,5=g 6,7=o)
    //      SHARED between groups A and B ----
    const float esc[4] = { -L1C, -L1C, L2C, -L1C };   // i,f,g,o exp2-domain scales
    half8v Bh[8], B2[8];
    #pragma unroll
    for (int n = 0; n < 8; ++n) {
        const int gc = n * 16 + m;           // gate row 0..127
        const float sc = esc[n >> 1];
        H8 bh;
        #pragma unroll
        for (int jj = 0; jj < 4; ++jj) {
            bh.h2[jj] = (half2v){ (_Float16)(sc * W_hh[gc * HID + quad * 8 + 2 * jj]),
                                  (_Float16)(sc * W_hh[gc * HID + quad * 8 + 2 * jj + 1]) };
        }
        Bh[n] = bh.h;
        H8 b2; b2.u[0] = b2.u[1] = b2.u[2] = b2.u[3] = 0u;
        if (quad == 0) {
            b2.h2[0] = (half2v){ (_Float16)(sc * W_ih[gc * 4 + 0]), (_Float16)(sc * W_ih[gc * 4 + 1]) };
            b2.h2[1] = (half2v){ (_Float16)(sc * W_ih[gc * 4 + 2]), (_Float16)(sc * W_ih[gc * 4 + 3]) };
            float bsum = sc * (b_ih[gc] + b_hh[gc]);
            _Float16 bhi = (_Float16)bsum;
            _Float16 blo = (_Float16)(bsum - (float)bhi);   // bias exact to ~2^-24
            b2.h2[2] = (half2v){ bhi, blo };                // K rows 4,5 (A = 1,1)
        }
        B2[n] = b2.h;
    }
    const unsigned int one2 = 0x3C003C00u;   // (1.0h, 1.0h)

    // ---- init h = 0 (LDS), c = 0 (regs) for both groups ----
    float cstA[2][4], cstB[2][4];
    #pragma unroll
    for (int hf = 0; hf < 2; ++hf)
        #pragma unroll
        for (int r = 0; r < 4; ++r) {
            cstA[hf][r] = 0.f; cstB[hf][r] = 0.f;
            hlA[quad * 4 + r][hf * 16 + m] = 0.f;
            hlB[quad * 4 + r][hf * 16 + m] = 0.f;
        }
    asm volatile("s_waitcnt lgkmcnt(0)" ::: "memory");

    // ---- encode: 200 steps, two independent groups interleaved ----
    const float4* xpA = (const float4*)(hist + (size_t)(elemA + m) * (SEQLEN * 4));
    const float4* xpB = (const float4*)(hist + (size_t)(elemB + m) * (SEQLEN * 4));
    float4 xvA = xpA[0];
    float4 xvB = xpB[0];
    #pragma unroll 1
    for (int t = 0; t < SEQLEN; ++t) {
        // --- A fragments ---
        float4 hA0 = *(const float4*)&hlA[m][quad * 8];
        float4 hA1 = *(const float4*)&hlA[m][quad * 8 + 4];
        H8 ahuA;
        ahuA.u[0] = pk(hA0.x, hA0.y); ahuA.u[1] = pk(hA0.z, hA0.w);
        ahuA.u[2] = pk(hA1.x, hA1.y); ahuA.u[3] = pk(hA1.z, hA1.w);
        const half8v ahA = ahuA.h;
        const unsigned int txA0 = pk(xvA.x, xvA.y), txA1 = pk(xvA.z, xvA.w);
        H8 a2uA;
        a2uA.u[0] = (quad == 0) ? txA0 : 0u;
        a2uA.u[1] = (quad == 0) ? txA1 : 0u;
        a2uA.u[2] = (quad == 0) ? one2 : 0u;
        a2uA.u[3] = 0u;
        const half8v a2A = a2uA.h;

        // --- B fragments ---
        float4 hB0 = *(const float4*)&hlB[m][quad * 8];
        float4 hB1 = *(const float4*)&hlB[m][quad * 8 + 4];
        H8 ahuB;
        ahuB.u[0] = pk(hB0.x, hB0.y); ahuB.u[1] = pk(hB0.z, hB0.w);
        ahuB.u[2] = pk(hB1.x, hB1.y); ahuB.u[3] = pk(hB1.z, hB1.w);
        const half8v ahB = ahuB.h;
        const unsigned int txB0 = pk(xvB.x, xvB.y), txB1 = pk(xvB.z, xvB.w);
        H8 a2uB;
        a2uB.u[0] = (quad == 0) ? txB0 : 0u;
        a2uB.u[1] = (quad == 0) ? txB1 : 0u;
        a2uB.u[2] = (quad == 0) ? one2 : 0u;
        a2uB.u[3] = 0u;
        const half8v a2B = a2uB.h;

        const int tn = (t + 1 < SEQLEN) ? t + 1 : SEQLEN - 1;
        float4 xnA = xpA[tn];                // prefetches stay in flight
        float4 xnB = xpB[tn];

        floatx4 accA[8], accB[8];
        #pragma unroll
        for (int n = 0; n < 8; ++n) {
            floatx4 a = __builtin_amdgcn_mfma_f32_16x16x32_f16(a2A, B2[n], (floatx4){0.f,0.f,0.f,0.f}, 0, 0, 0);
            accA[n] = __builtin_amdgcn_mfma_f32_16x16x32_f16(ahA, Bh[n], a, 0, 0, 0);
        }
        #pragma unroll
        for (int n = 0; n < 8; ++n) {
            floatx4 a = __builtin_amdgcn_mfma_f32_16x16x32_f16(a2B, B2[n], (floatx4){0.f,0.f,0.f,0.f}, 0, 0, 0);
            accB[n] = __builtin_amdgcn_mfma_f32_16x16x32_f16(ahB, Bh[n], a, 0, 0, 0);
        }

        // --- gates A (exp2 domain, paired rcps) ---
        #pragma unroll
        for (int hf = 0; hf < 2; ++hf) {
            #pragma unroll
            for (int pr = 0; pr < 2; ++pr) {
                const int r0 = pr * 2, r1 = r0 + 1;
                const float eiA = EXP2(accA[0 + hf][r0]), eiB = EXP2(accA[0 + hf][r1]);
                const float efA = EXP2(accA[2 + hf][r0]), efB = EXP2(accA[2 + hf][r1]);
                const float egA = EXP2(accA[4 + hf][r0]), egB = EXP2(accA[4 + hf][r1]);
                const float eoA = EXP2(accA[6 + hf][r0]), eoB = EXP2(accA[6 + hf][r1]);
                const float pfA = 1.f + efA,                  pfB = 1.f + efB;
                const float t1A = (1.f + eiA) * (1.f + egA),  t1B = (1.f + eiB) * (1.f + egB);
                const float numA = fmaf(cstA[hf][r0], t1A, (egA - 1.f) * pfA);
                const float numB = fmaf(cstA[hf][r1], t1B, (egB - 1.f) * pfB);
                const float dA = t1A * pfA, dB = t1B * pfB;   // <= 2^52 each
                const float R  = RCPF(dA * dB);               // <= 2^104: safe
                const float cnA = numA * (R * dB);
                const float cnB = numB * (R * dA);
                const float ecA = EXP2(MED3(cnA, -12.f, 12.f) * L2C);
                const float ecB = EXP2(MED3(cnB, -12.f, 12.f) * L2C);
                const float dhA = (1.f + eoA) * (1.f + ecA);
                const float dhB = (1.f + eoB) * (1.f + ecB);
                const float Rh  = RCPF(dhA * dhB);
                const float hnA = (ecA - 1.f) * (Rh * dhB);
                const float hnB = (ecB - 1.f) * (Rh * dhA);

                cstA[hf][r0] = cnA; cstA[hf][r1] = cnB;       // state UNclamped
                hlA[quad * 4 + r0][hf * 16 + m] = hnA;
                hlA[quad * 4 + r1][hf * 16 + m] = hnB;
            }
        }
        // --- gates B ---
        #pragma unroll
        for (int hf = 0; hf < 2; ++hf) {
            #pragma unroll
            for (int pr = 0; pr < 2; ++pr) {
                const int r0 = pr * 2, r1 = r0 + 1;
                const float eiA = EXP2(accB[0 + hf][r0]), eiB = EXP2(accB[0 + hf][r1]);
                const float efA = EXP2(accB[2 + hf][r0]), efB = EXP2(accB[2 + hf][r1]);
                const float egA = EXP2(accB[4 + hf][r0]), egB = EXP2(accB[4 + hf][r1]);
                const float eoA = EXP2(accB[6 + hf][r0]), eoB = EXP2(accB[6 + hf][r1]);
                const float pfA = 1.f + efA,                  pfB = 1.f + efB;
                const float t1A = (1.f + eiA) * (1.f + egA),  t1B = (1.f + eiB) * (1.f + egB);
                const float numA = fmaf(cstB[hf][r0], t1A, (egA - 1.f) * pfA);
                const float numB = fmaf(cstB[hf][r1], t1B, (egB - 1.f) * pfB);
                const float dA = t1A * pfA, dB = t1B * pfB;
                const float R  = RCPF(dA * dB);
                const float cnA = numA * (R * dB);
                const float cnB = numB * (R * dA);
                const float ecA = EXP2(MED3(cnA, -12.f, 12.f) * L2C);
                const float ecB = EXP2(MED3(cnB, -12.f, 12.f) * L2C);
                const float dhA = (1.f + eoA) * (1.f + ecA);
                const float dhB = (1.f + eoB) * (1.f + ecB);
                const float Rh  = RCPF(dhA * dhB);
                const float hnA = (ecA - 1.f) * (Rh * dhB);
                const float hnB = (ecB - 1.f) * (Rh * dhA);

                cstB[hf][r0] = cnA; cstB[hf][r1] = cnB;
                hlB[quad * 4 + r0][hf * 16 + m] = hnA;
                hlB[quad * 4 + r1][hf * 16 + m] = hnB;
            }
        }
        asm volatile("s_waitcnt lgkmcnt(0)" ::: "memory");  // DS in-order per wave
        xvA = xnA; xvB = xnB;
    }

    // ---- decode: 50 steps (c reset to 0 -> f-gate dead; tiles 2,3 skipped) ----
    float wp[4][8];
    #pragma unroll
    for (int d = 0; d < 4; ++d)
        #pragma unroll
        for (int j = 0; j < 8; ++j) wp[d][j] = W_pred[d * HID + quad * 8 + j];
    float bp[4] = { b_pred[0], b_pred[1], b_pred[2], b_pred[3] };

    float* opA = out + (size_t)(elemA + m) * (PSTEPS * 4);
    float* opB = out + (size_t)(elemB + m) * (PSTEPS * 4);
    #pragma unroll 1
    for (int ps = 0; ps < PSTEPS; ++ps) {
        float4 hA0 = *(const float4*)&hlA[m][quad * 8];
        float4 hA1 = *(const float4*)&hlA[m][quad * 8 + 4];
        const float hvA[8] = { hA0.x, hA0.y, hA0.z, hA0.w, hA1.x, hA1.y, hA1.z, hA1.w };
        float4 hB0 = *(const float4*)&hlB[m][quad * 8];
        float4 hB1 = *(const float4*)&hlB[m][quad * 8 + 4];
        const float hvB[8] = { hB0.x, hB0.y, hB0.z, hB0.w, hB1.x, hB1.y, hB1.z, hB1.w };

        float pdA[4], pdB[4];
        #pragma unroll
        for (int d = 0; d < 4; ++d) {
            float sA = 0.f, sB = 0.f;
            #pragma unroll
            for (int j = 0; j < 8; ++j) { sA = fmaf(hvA[j], wp[d][j], sA); sB = fmaf(hvB[j], wp[d][j], sB); }
            sA += __shfl_xor(sA, 16); sA += __shfl_xor(sA, 32);
            sB += __shfl_xor(sB, 16); sB += __shfl_xor(sB, 32);
            pdA[d] = sA + bp[d];
            pdB[d] = sB + bp[d];
        }
        if (quad == 0) {
            *(float4*)(opA + ps * 4) = make_float4(pdA[0], pdA[1], pdA[2], pdA[3]);
            *(float4*)(opB + ps * 4) = make_float4(pdB[0], pdB[1], pdB[2], pdB[3]);
        }

        if (ps + 1 < PSTEPS) {
            H8 ahuA;
            ahuA.u[0] = pk(hvA[0], hvA[1]); ahuA.u[1] = pk(hvA[2], hvA[3]);
            ahuA.u[2] = pk(hvA[4], hvA[5]); ahuA.u[3] = pk(hvA[6], hvA[7]);
            const half8v ahA = ahuA.h;
            const unsigned int txA0 = pk(pdA[0], pdA[1]), txA1 = pk(pdA[2], pdA[3]);
            H8 a2uA;
            a2uA.u[0] = (quad == 0) ? txA0 : 0u;
            a2uA.u[1] = (quad == 0) ? txA1 : 0u;
            a2uA.u[2] = (quad == 0) ? one2 : 0u;
            a2uA.u[3] = 0u;
            const half8v a2A = a2uA.h;

            H8 ahuB;
            ahuB.u[0] = pk(hvB[0], hvB[1]); ahuB.u[1] = pk(hvB[2], hvB[3]);
            ahuB.u[2] = pk(hvB[4], hvB[5]); ahuB.u[3] = pk(hvB[6], hvB[7]);
            const half8v ahB = ahuB.h;
            const unsigned int txB0 = pk(pdB[0], pdB[1]), txB1 = pk(pdB[2], pdB[3]);
            H8 a2uB;
            a2uB.u[0] = (quad == 0) ? txB0 : 0u;
            a2uB.u[1] = (quad == 0) ? txB1 : 0u;
            a2uB.u[2] = (quad == 0) ? one2 : 0u;
            a2uB.u[3] = 0u;
            const half8v a2B = a2uB.h;

            floatx4 accA[6], accB[6];   // tiles 0,1=i ; 4,5=g ; 6,7=o
            #pragma unroll
            for (int nn = 0; nn < 6; ++nn) {
                const int n = (nn < 2) ? nn : nn + 2;
                floatx4 a = __builtin_amdgcn_mfma_f32_16x16x32_f16(a2A, B2[n], (floatx4){0.f,0.f,0.f,0.f}, 0, 0, 0);
                accA[nn] = __builtin_amdgcn_mfma_f32_16x16x32_f16(ahA, Bh[n], a, 0, 0, 0);
            }
            #pragma unroll
            for (int nn = 0; nn < 6; ++nn) {
                const int n = (nn < 2) ? nn : nn + 2;
                floatx4 a = __builtin_amdgcn_mfma_f32_16x16x32_f16(a2B, B2[n], (floatx4){0.f,0.f,0.f,0.f}, 0, 0, 0);
                accB[nn] = __builtin_amdgcn_mfma_f32_16x16x32_f16(ahB, Bh[n], a, 0, 0, 0);
            }

            #pragma unroll
            for (int hf = 0; hf < 2; ++hf) {
                #pragma unroll
                for (int pr = 0; pr < 2; ++pr) {
                    const int r0 = pr * 2, r1 = r0 + 1;
                    const float eiA = EXP2(accA[0 + hf][r0]), eiB = EXP2(accA[0 + hf][r1]);
                    const float egA = EXP2(accA[2 + hf][r0]), egB = EXP2(accA[2 + hf][r1]);
                    const float eoA = EXP2(accA[4 + hf][r0]), eoB = EXP2(accA[4 + hf][r1]);
                    const float dA = (1.f + eiA) * (1.f + egA);
                    const float dB = (1.f + eiB) * (1.f + egB);
                    const float R  = RCPF(dA * dB);
                    const float cnA = (egA - 1.f) * (R * dB);
                    const float cnB = (egB - 1.f) * (R * dA);
                    const float ecA = EXP2(cnA * L2C);        // ec in [2^-2.9, 2^2.9]
                    const float ecB = EXP2(cnB * L2C);
                    const float dhA = (1.f + eoA) * (1.f + ecA);
                    const float dhB = (1.f + eoB) * (1.f + ecB);
                    const float Rh  = RCPF(dhA * dhB);
                    const float hnA = (ecA - 1.f) * (Rh * dhB);
                    const float hnB = (ecB - 1.f) * (Rh * dhA);

                    hlA[quad * 4 + r0][hf * 16 + m] = hnA;
                    hlA[quad * 4 + r1][hf * 16 + m] = hnB;
                }
            }
            #pragma unroll
            for (int hf = 0; hf < 2; ++hf) {
                #pragma unroll
                for (int pr = 0; pr < 2; ++pr) {
                    const int r0 = pr * 2, r1 = r0 + 1;
                    const float eiA = EXP2(accB[0 + hf][r0]), eiB = EXP2(accB[0 + hf][r1]);
                    const float egA = EXP2(accB[2 + hf][r0]), egB = EXP2(accB[2 + hf][r1]);
                    const float eoA = EXP2(accB[4 + hf][r0]), eoB = EXP2(accB[4 + hf][r1]);
                    const float dA = (1.f + eiA) * (1.f + egA);
                    const float dB = (1.f + eiB) * (1.f + egB);
                    const float R  = RCPF(dA * dB);
                    const float cnA = (egA - 1.f) * (R * dB);
                    const float cnB = (egB - 1.f) * (R * dA);
                    const float ecA = EXP2(cnA * L2C);
                    const float ecB = EXP2(cnB * L2C);
                    const float dhA = (1.f + eoA) * (1.f + ecA);
                    const float dhB = (1.f + eoB) * (1.f + ecB);
                    const float Rh  = RCPF(dhA * dhB);
                    const float hnA = (ecA - 1.f) * (Rh * dhB);
                    const float hnB = (ecB - 1.f) * (Rh * dhA);

                    hlB[quad * 4 + r0][hf * 16 + m] = hnA;
                    hlB[quad * 4 + r1][hf * 16 + m] = hnB;
                }
            }
            asm volatile("s_waitcnt lgkmcnt(0)" ::: "memory");
        }
    }
}

extern "C" void kernel_launch(void* const* d_in, const int* in_sizes, int n_in,
                              void* d_out, int out_size, void* d_ws, size_t ws_size,
                              hipStream_t stream) {
    const float* hist   = (const float*)d_in[0];
    const float* W_ih   = (const float*)d_in[1];
    const float* W_hh   = (const float*)d_in[2];
    const float* b_ih   = (const float*)d_in[3];
    const float* b_hh   = (const float*)d_in[4];
    const float* W_pred = (const float*)d_in[5];
    const float* b_pred = (const float*)d_in[6];
    float* out = (float*)d_out;

    const int blocks = BATCH / 128;   // 256 blocks x 4 waves x 2 groups x 16 batches
    lstm_mfma_kernel<<<blocks, 256, 0, stream>>>(hist, W_ih, W_hh, b_ih, b_hh,
                                                 W_pred, b_pred, out);
}

// Round 4
// 373.115 us; speedup vs baseline: 1.2303x; 1.2303x over previous
//
#include <hip/hip_runtime.h>
#include <math.h>

#define BATCH 32768
#define SEQLEN 200
#define PSTEPS 50
#define HID 32
#define LDS_PAD 36   // float row stride 36 -> mild bank aliasing only (m136)

typedef __attribute__((ext_vector_type(2))) _Float16 half2v;
typedef __attribute__((ext_vector_type(8))) _Float16 half8v;
typedef __attribute__((ext_vector_type(2))) __fp16   fp16x2;   // cvt_pkrtz return type
typedef __attribute__((ext_vector_type(4))) float floatx4;
typedef __attribute__((ext_vector_type(2))) float float2v;

#define EXP2 __builtin_amdgcn_exp2f      // v_exp_f32: 2^x
#define RCPF __builtin_amdgcn_rcpf       // v_rcp_f32
#define PKRTZ __builtin_amdgcn_cvt_pkrtz // v_cvt_pkrtz_f16_f32
#define MED3 __builtin_amdgcn_fmed3f     // v_med3_f32
#define FMA2 __builtin_elementwise_fma   // <2 x float> fma -> v_pk_fma_f32

#define L1C 1.4426950408889634f          // log2(e)
#define L2C 2.8853900817779268f          // 2*log2(e)

union H8 { unsigned int u[4]; half8v h; half2v h2[4]; };
union HU { fp16x2 h; unsigned int u; };

__device__ __forceinline__ unsigned int pk(float a, float b) {
    HU t; t.h = PKRTZ(a, b); return t.u;
}

// R14 = R10 structure (one wave = private 16-batch group, private LDS
// h-region, NO barriers, 2 waves/SIMD — the best measured config) with two
// VALU-pipe cuts:
//  1. per-step `s_waitcnt lgkmcnt(0)` REMOVED: DS ops of a wave execute
//     in-order in the DS pipe, and the compiler can't hoist the next
//     step's ds_read above the may-aliasing ds_writes — so RAW through
//     LDS needs no explicit drain. The old asm stalled ~100 cyc/step
//     waiting for write commit before issuing the reads.
//  2. gate math packed as float2 over the (A,B) cell pair ->
//     v_pk_{fma,mul,add}_f32 (full-rate 2-wide on gfx950). Elementwise
//     identical to the scalar pair: results bit-identical to R10.
// Per-cell arithmetic otherwise token-for-token R10: exp-domain scales
// folded into weights, paired rcp, med3 tanh clamp (EXACT: tanh(12)==1.0f
// in fp32), state c unclamped, bias hi/lo split, decode f-gate skipped,
// anti-phase s_sleep stagger for the co-resident block pair.
// C layout: row(batch)=quad*4+reg, col(gate)=lane&15; A: m=lane&15, k=quad*8+j.
__global__ __launch_bounds__(256, 2)
void lstm_mfma_kernel(const float* __restrict__ hist, const float* __restrict__ W_ih,
                      const float* __restrict__ W_hh, const float* __restrict__ b_ih,
                      const float* __restrict__ b_hh, const float* __restrict__ W_pred,
                      const float* __restrict__ b_pred, float* __restrict__ out)
{
    const int lane = threadIdx.x & 63;
    const int wv   = threadIdx.x >> 6;
    const int m    = lane & 15;
    const int quad = lane >> 4;
    const int elem0 = (blockIdx.x * 4 + wv) * 16;

    // anti-phase: co-resident pair assumed (k, k+256) for 512-block grid
    if ((blockIdx.x >> 8) & 1) __builtin_amdgcn_s_sleep(12);

    __shared__ __align__(16) float h_lds_all[4][16][LDS_PAD];
    float (*hl)[LDS_PAD] = h_lds_all[wv];    // per-wave region: no __syncthreads ever

    // ---- resident weight fragments (f16, exp-scale folded; tiles 0,1=i 2,3=f 4,5=g 6,7=o) ----
    const float esc[4] = { -L1C, -L1C, L2C, -L1C };   // i,f,g,o exp2-domain scales
    half8v Bh[8], B2[8];
    #pragma unroll
    for (int n = 0; n < 8; ++n) {
        const int gc = n * 16 + m;           // gate row 0..127
        const float sc = esc[n >> 1];
        H8 bh;
        #pragma unroll
        for (int jj = 0; jj < 4; ++jj) {
            bh.h2[jj] = (half2v){ (_Float16)(sc * W_hh[gc * HID + quad * 8 + 2 * jj]),
                                  (_Float16)(sc * W_hh[gc * HID + quad * 8 + 2 * jj + 1]) };
        }
        Bh[n] = bh.h;
        H8 b2; b2.u[0] = b2.u[1] = b2.u[2] = b2.u[3] = 0u;
        if (quad == 0) {
            b2.h2[0] = (half2v){ (_Float16)(sc * W_ih[gc * 4 + 0]), (_Float16)(sc * W_ih[gc * 4 + 1]) };
            b2.h2[1] = (half2v){ (_Float16)(sc * W_ih[gc * 4 + 2]), (_Float16)(sc * W_ih[gc * 4 + 3]) };
            float bsum = sc * (b_ih[gc] + b_hh[gc]);
            _Float16 bhi = (_Float16)bsum;
            _Float16 blo = (_Float16)(bsum - (float)bhi);   // bias exact to ~2^-24
            b2.h2[2] = (half2v){ bhi, blo };                // K rows 4,5 (A = 1,1)
        }
        B2[n] = b2.h;
    }
    const unsigned int one2 = 0x3C003C00u;   // (1.0h, 1.0h)
    const floatx4 zf4 = { 0.f, 0.f, 0.f, 0.f };

    // ---- init h = 0 (LDS), c = 0 (regs) ----
    float cst[2][4];
    #pragma unroll
    for (int hf = 0; hf < 2; ++hf)
        #pragma unroll
        for (int r = 0; r < 4; ++r) { cst[hf][r] = 0.f; hl[quad * 4 + r][hf * 16 + m] = 0.f; }
    // no drain needed: DS pipe is in-order per wave

    // ---- encode: 200 steps ----
    const float4* xp = (const float4*)(hist + (size_t)(elem0 + m) * (SEQLEN * 4));
    float4 xv = xp[0];
    #pragma unroll 1
    for (int t = 0; t < SEQLEN; ++t) {
        float4 h0 = *(const float4*)&hl[m][quad * 8];
        float4 h1 = *(const float4*)&hl[m][quad * 8 + 4];
        H8 ahu;
        ahu.u[0] = pk(h0.x, h0.y); ahu.u[1] = pk(h0.z, h0.w);
        ahu.u[2] = pk(h1.x, h1.y); ahu.u[3] = pk(h1.z, h1.w);
        const half8v ah = ahu.h;

        const unsigned int tx0 = pk(xv.x, xv.y), tx1 = pk(xv.z, xv.w);
        H8 a2u;
        a2u.u[0] = (quad == 0) ? tx0 : 0u;
        a2u.u[1] = (quad == 0) ? tx1 : 0u;
        a2u.u[2] = (quad == 0) ? one2 : 0u;
        a2u.u[3] = 0u;
        const half8v a2 = a2u.h;

        const int tn = (t + 1 < SEQLEN) ? t + 1 : SEQLEN - 1;
        float4 xn = xp[tn];                  // prefetch stays in flight

        floatx4 acc[8];
        #pragma unroll
        for (int n = 0; n < 8; ++n) {
            floatx4 a = __builtin_amdgcn_mfma_f32_16x16x32_f16(a2, B2[n], zf4, 0, 0, 0);
            acc[n] = __builtin_amdgcn_mfma_f32_16x16x32_f16(ah, Bh[n], a, 0, 0, 0);
        }
        // gates arrive in exp2 domain; cell pairs packed as float2 -> v_pk_* ops
        #pragma unroll
        for (int hf = 0; hf < 2; ++hf) {
            #pragma unroll
            for (int pr = 0; pr < 2; ++pr) {
                const int r0 = pr * 2, r1 = r0 + 1;
                const float2v ei = { EXP2(acc[0 + hf][r0]), EXP2(acc[0 + hf][r1]) };
                const float2v ef = { EXP2(acc[2 + hf][r0]), EXP2(acc[2 + hf][r1]) };
                const float2v eg = { EXP2(acc[4 + hf][r0]), EXP2(acc[4 + hf][r1]) };
                const float2v eo = { EXP2(acc[6 + hf][r0]), EXP2(acc[6 + hf][r1]) };
                // cn = c/(1+ef) + (eg-1)/((1+ei)(1+eg)) ; rcp shared across pair
                const float2v pf = 1.f + ef;
                const float2v t1 = (1.f + ei) * (1.f + eg);
                const float2v cc = { cst[hf][r0], cst[hf][r1] };
                const float2v num = FMA2(cc, t1, (eg - 1.f) * pf);
                const float2v d  = t1 * pf;                 // <= 2^52 each
                const float   R  = RCPF(d.x * d.y);         // <= 2^104: safe
                const float2v dsw = { d.y, d.x };
                const float2v cn  = num * (R * dsw);
                // tanh input clamp +-12: EXACT (tanh(12)==1.0f in fp32)
                const float2v cna = { MED3(cn.x, -12.f, 12.f), MED3(cn.y, -12.f, 12.f) };
                const float2v ea  = cna * L2C;
                const float2v ec  = { EXP2(ea.x), EXP2(ea.y) };
                const float2v dh  = (1.f + eo) * (1.f + ec);
                const float   Rh  = RCPF(dh.x * dh.y);
                const float2v dhsw = { dh.y, dh.x };
                const float2v hn  = (ec - 1.f) * (Rh * dhsw);

                cst[hf][r0] = cn.x; cst[hf][r1] = cn.y;     // state UNclamped (matches ref)
                hl[quad * 4 + r0][hf * 16 + m] = hn.x;
                hl[quad * 4 + r1][hf * 16 + m] = hn.y;
            }
        }
        // no lgkmcnt drain: DS in-order per wave; compiler can't hoist the
        // may-aliasing next-step reads above these writes
        xv = xn;
    }

    // ---- decode: 50 steps (c reset to 0 -> f-gate dead; tiles 2,3 skipped) ----
    float wp[4][8];
    #pragma unroll
    for (int d = 0; d < 4; ++d)
        #pragma unroll
        for (int j = 0; j < 8; ++j) wp[d][j] = W_pred[d * HID + quad * 8 + j];
    float bp[4] = { b_pred[0], b_pred[1], b_pred[2], b_pred[3] };

    float* op = out + (size_t)(elem0 + m) * (PSTEPS * 4);
    #pragma unroll 1
    for (int p = 0; p < PSTEPS; ++p) {
        float4 h0 = *(const float4*)&hl[m][quad * 8];
        float4 h1 = *(const float4*)&hl[m][quad * 8 + 4];
        const float hv[8] = { h0.x, h0.y, h0.z, h0.w, h1.x, h1.y, h1.z, h1.w };

        float pd[4];
        #pragma unroll
        for (int d = 0; d < 4; ++d) {
            float s = 0.f;
            #pragma unroll
            for (int j = 0; j < 8; ++j) s = fmaf(hv[j], wp[d][j], s);
            s += __shfl_xor(s, 16);
            s += __shfl_xor(s, 32);
            pd[d] = s + bp[d];
        }
        if (quad == 0) *(float4*)(op + p * 4) = make_float4(pd[0], pd[1], pd[2], pd[3]);

        if (p + 1 < PSTEPS) {
            H8 ahu;
            ahu.u[0] = pk(hv[0], hv[1]); ahu.u[1] = pk(hv[2], hv[3]);
            ahu.u[2] = pk(hv[4], hv[5]); ahu.u[3] = pk(hv[6], hv[7]);
            const half8v ah = ahu.h;
            const unsigned int tx0 = pk(pd[0], pd[1]), tx1 = pk(pd[2], pd[3]);
            H8 a2u;
            a2u.u[0] = (quad == 0) ? tx0 : 0u;
            a2u.u[1] = (quad == 0) ? tx1 : 0u;
            a2u.u[2] = (quad == 0) ? one2 : 0u;
            a2u.u[3] = 0u;
            const half8v a2 = a2u.h;

            floatx4 acc[6];   // tiles 0,1=i ; 4,5=g ; 6,7=o
            #pragma unroll
            for (int nn = 0; nn < 6; ++nn) {
                const int n = (nn < 2) ? nn : nn + 2;
                floatx4 a = __builtin_amdgcn_mfma_f32_16x16x32_f16(a2, B2[n], zf4, 0, 0, 0);
                acc[nn] = __builtin_amdgcn_mfma_f32_16x16x32_f16(ah, Bh[n], a, 0, 0, 0);
            }
            #pragma unroll
            for (int hf = 0; hf < 2; ++hf) {
                #pragma unroll
                for (int pr = 0; pr < 2; ++pr) {
                    const int r0 = pr * 2, r1 = r0 + 1;
                    const float2v ei = { EXP2(acc[0 + hf][r0]), EXP2(acc[0 + hf][r1]) };
                    const float2v eg = { EXP2(acc[2 + hf][r0]), EXP2(acc[2 + hf][r1]) };
                    const float2v eo = { EXP2(acc[4 + hf][r0]), EXP2(acc[4 + hf][r1]) };
                    // cn = (eg-1)/((1+ei)(1+eg)) (c==0); |cn|<1
                    const float2v d  = (1.f + ei) * (1.f + eg);
                    const float   R  = RCPF(d.x * d.y);
                    const float2v dsw = { d.y, d.x };
                    const float2v cn  = (eg - 1.f) * (R * dsw);
                    const float2v ea  = cn * L2C;
                    const float2v ec  = { EXP2(ea.x), EXP2(ea.y) };   // ec in [2^-2.9, 2^2.9]
                    const float2v dh  = (1.f + eo) * (1.f + ec);
                    const float   Rh  = RCPF(dh.x * dh.y);
                    const float2v dhsw = { dh.y, dh.x };
                    const float2v hn  = (ec - 1.f) * (Rh * dhsw);

                    hl[quad * 4 + r0][hf * 16 + m] = hn.x;
                    hl[quad * 4 + r1][hf * 16 + m] = hn.y;
                }
            }
            // no lgkmcnt drain (DS in-order per wave)
        }
    }
}

extern "C" void kernel_launch(void* const* d_in, const int* in_sizes, int n_in,
                              void* d_out, int out_size, void* d_ws, size_t ws_size,
                              hipStream_t stream) {
    const float* hist   = (const float*)d_in[0];
    const float* W_ih   = (const float*)d_in[1];
    const float* W_hh   = (const float*)d_in[2];
    const float* b_ih   = (const float*)d_in[3];
    const float* b_hh   = (const float*)d_in[4];
    const float* W_pred = (const float*)d_in[5];
    const float* b_pred = (const float*)d_in[6];
    float* out = (float*)d_out;

    const int blocks = (BATCH / 16) / 4;   // 512 blocks = 2048 waves, 2/SIMD
    lstm_mfma_kernel<<<blocks, 256, 0, stream>>>(hist, W_ih, W_hh, b_ih, b_hh,
                                                 W_pred, b_pred, out);
}